// Round 12
// baseline (1471.820 us; speedup 1.0000x reference)
//
#include <hip/hip_runtime.h>
#include <hip/hip_bf16.h>

#define N_NODES 10000
#define N_EDGES 160000

typedef __bf16 bf16x8 __attribute__((ext_vector_type(8)));
typedef float  f32x4  __attribute__((ext_vector_type(4)));
typedef unsigned short u16x8 __attribute__((ext_vector_type(8)));
union U16x8 { u16x8 u; bf16x8 b; };

__device__ __forceinline__ float sigf(float x){ return 1.0f/(1.0f+__expf(-x)); }
__device__ __forceinline__ float siluf(float x){ return x*sigf(x); }

__device__ __forceinline__ unsigned int f2bfbits(float f){
  unsigned int u = __float_as_uint(f);
  return (u + 0x7fffu + ((u>>16)&1u)) >> 16;
}
__device__ __forceinline__ void split3(float v, unsigned short* h, unsigned short* m, unsigned short* lo){
  unsigned int hb = f2bfbits(v); float hf = __uint_as_float(hb<<16);
  float r1 = v - hf;
  unsigned int mb = f2bfbits(r1); float mf = __uint_as_float(mb<<16);
  unsigned int lb = f2bfbits(r1 - mf);
  *h=(unsigned short)hb; *m=(unsigned short)mb; *lo=(unsigned short)lb;
}

// d' (permuted message dim) -> d (reference mji dim). d' = c*8 + slot.
__device__ __forceinline__ int dmap(int dp){
  int c = dp>>3, slot = dp&7;
  if (slot==0) return c;
  if (slot==1) return 128+c;
  if (slot<5)  return 256+3*c+(slot-2);
  return 640+3*c+(slot-5);
}

// ---------------- pack weights: TRIPLE-split bf16 B-fragments (verified R10) ----------------
__global__ void pack_weights(const float* __restrict__ Wr4,
                             const float* __restrict__ Wse1,
                             const float* __restrict__ Wse2,
                             unsigned short* __restrict__ wr4pk,
                             unsigned short* __restrict__ wse1pk,
                             unsigned short* __restrict__ wse2pk)
{
  int t = blockIdx.x*256 + threadIdx.x;   // 0..32767
  int j = t&7, l = (t>>3)&63;
  int lg = l>>4, lm = l&15;
  { // wr4pk
    int ks = (t>>9)&1; int nt = t>>10;
    int k = ks*32 + lg*8 + j;
    int col = nt*16 + lm;
    split3(Wr4[k*512+col]*0.125f, wr4pk+t, wr4pk+t+32768, wr4pk+t+65536);
  }
  { // wse1pk
    int kb = (t>>9)&31; int nt = t>>14;
    int d = dmap(kb*32 + lg*8 + j);
    int col = nt*16 + lm;
    split3(Wse1[d*32+col], wse1pk+t, wse1pk+t+32768, wse1pk+t+65536);
  }
  { // wse2pk
    int nt = t>>9;
    int krow = lg*8 + j;
    int d = dmap(nt*16 + lm);
    split3(Wse2[krow*1024+d], wse2pk+t, wse2pk+t+32768, wse2pk+t+65536);
  }
}

// ---------------- node up-projection (exact R6) ----------------
__global__ __launch_bounds__(128) void node_up_kernel(
    const float* __restrict__ nf, const float* __restrict__ W0, const float* __restrict__ W1,
    float* __restrict__ s_up, float* __restrict__ v_up)
{
  int n = blockIdx.x; int c = threadIdx.x;
  __shared__ float row[512];
  #pragma unroll
  for (int i=0;i<4;i++) row[c + 128*i] = nf[n*512 + c + 128*i];
  __syncthreads();
  float as=0.f, a0=0.f, a1=0.f, a2=0.f;
  for (int u=0;u<128;u++){
    float w0 = W0[u*128+c], w1 = W1[u*128+c];
    as += row[u]*w0;
    a0 += row[128+u*3+0]*w1;
    a1 += row[128+u*3+1]*w1;
    a2 += row[128+u*3+2]*w1;
  }
  const float f = 0.08838834764831845f;   // 1/sqrt(128)
  s_up[n*128+c] = as*f;
  v_up[n*384 + c*3+0] = a0*f;
  v_up[n*384 + c*3+1] = a1*f;
  v_up[n*384 + c*3+2] = a2*f;
}

// ---------------- fused edge kernel: R10 body, 74.1KB LDS, natural VGPR ----------------
// 1024 threads, 16 edges/block. LDS layout (bytes):
//  [0,65536)       : mji f32 [16 e][1024 d'], vec-XOR-swizzled (see mjivec)
//                    [0,8192) doubles as hA/hB f32 scratch during P1 (dead before P2 writes)
//  [65536,67584)   : h3 hi bf16 [16][64], XOR-swizzled: byte ^= (row&7)<<4
//  [67584,69632)   : h3 lo
//  [69632,71680)   : partial f32 [16][32] (LDS-atomic reduce target)
//  [71680,72704)   : sg1 hi bf16 [16][32]
//  [72704,73728)   : sg1 lo
//  [73728,...)     : s_src[16], s_dst[16], s_y[16][4]
#define OFF_MJI  0
#define OFF_H3H  65536
#define OFF_H3L  67584
#define OFF_PART 69632
#define OFF_SG1H 71680
#define OFF_SG1L 72704
#define OFF_SRC  73728
#define OFF_DST  73792
#define OFF_Y    73856

__global__ __launch_bounds__(1024, 1) void edge_kernel(
    const float* __restrict__ ef, const float* __restrict__ ea, const int* __restrict__ ei,
    const float* __restrict__ Wr1, const float* __restrict__ Wr2, const float* __restrict__ Wr3,
    const unsigned short* __restrict__ wr4pk, const unsigned short* __restrict__ wse1pk,
    const unsigned short* __restrict__ wse2pk,
    const float* __restrict__ s_up, const float* __restrict__ v_up, float* __restrict__ accg)
{
  __shared__ __align__(16) char smem[74112];
  float* hA = (float*)smem;                // P1 scratch, aliases mji
  float* hB = (float*)(smem + 4096);
  float* partial = (float*)(smem + OFF_PART);
  int*   s_src = (int*)(smem + OFF_SRC);
  int*   s_dst = (int*)(smem + OFF_DST);
  float* s_y   = (float*)(smem + OFF_Y);

  const int t = threadIdx.x;
  const int e0 = blockIdx.x * 16;
  const int l = t & 63, w = t >> 6;        // lane, wave (0..15)
  const int lg = l >> 4, lm = l & 15;

  // swizzled mji accessor: v = f32x4 index in [0,4096)
  auto mjivec = [&](int v) -> float* {
    int p = v ^ ((v>>3)&7) ^ ((v>>8)&7);
    return (float*)(smem + OFF_MJI + p*16);
  };

  if (t < 16){ s_src[t] = ei[e0+t]; s_dst[t] = ei[N_EDGES + e0 + t]; }
  else if (t >= 64 && t < 128){ int q=t-64; s_y[(q>>2)*4 + (q&3)] = ea[(e0+(q>>2))*4 + (q&3)]; }
  if (t >= 512) partial[t-512] = 0.f;      // zero reduce target (barrier-ordered before P3)

  // ---- P1 (R10): MLP 8->64->64->64 (+silu); h3 -> hi/lo bf16 (swizzled) ----
  {
    const int i = t & 63, eh = t >> 6;
    float r;
    { float a0=0.f;
      #pragma unroll
      for (int k=0;k<8;k++) a0 += ef[(e0+eh)*8+k]*Wr1[k*64+i];
      r = siluf(a0*0.35355339059327373f);
    }
    hA[eh*64+i]=r;
    __syncthreads();
    { float a0=0.f;
      for (int k=0;k<64;k++) a0 += hA[eh*64+k]*Wr2[k*64+i];
      r = siluf(a0*0.125f);
    }
    hB[eh*64+i]=r;
    __syncthreads();
    { float a0=0.f;
      for (int k=0;k<64;k++) a0 += hB[eh*64+k]*Wr3[k*64+i];
      r = siluf(a0*0.125f);
    }
    unsigned int hb = f2bfbits(r);
    unsigned int lb = f2bfbits(r - __uint_as_float(hb<<16));
    int o = (eh*128 + i*2) ^ ((eh&7)<<4);
    *(unsigned short*)(smem + OFF_H3H + o) = (unsigned short)hb;
    *(unsigned short*)(smem + OFF_H3L + o) = (unsigned short)lb;
  }
  __syncthreads();

  // ---- P2 (waves 0..7, MFMA A hi/lo x B triple): tpw + messages -> mji f32 (swizzled) ----
  if (w < 8) {
    int oa0 = (lm*128 +  0 + lg*16) ^ ((lm&7)<<4);
    int oa1 = (lm*128 + 64 + lg*16) ^ ((lm&7)<<4);
    bf16x8 a0h = *(const bf16x8*)(smem + OFF_H3H + oa0);
    bf16x8 a1h = *(const bf16x8*)(smem + OFF_H3H + oa1);
    bf16x8 a0l = *(const bf16x8*)(smem + OFF_H3L + oa0);
    bf16x8 a1l = *(const bf16x8*)(smem + OFF_H3L + oa1);
    f32x4 tq[4];
    #pragma unroll
    for (int q=0;q<4;q++){
      int nt = q*8 + w;                    // wave w owns cols q*128 + w*16 + lm for all q
      const unsigned short* bp0 = wr4pk + (nt*2+0)*512 + l*8;
      const unsigned short* bp1 = wr4pk + (nt*2+1)*512 + l*8;
      bf16x8 b0h = *(const bf16x8*)(bp0);
      bf16x8 b0m = *(const bf16x8*)(bp0+32768);
      bf16x8 b0l = *(const bf16x8*)(bp0+65536);
      bf16x8 b1h = *(const bf16x8*)(bp1);
      bf16x8 b1m = *(const bf16x8*)(bp1+32768);
      bf16x8 b1l = *(const bf16x8*)(bp1+65536);
      f32x4 acc = {0.f,0.f,0.f,0.f};
      acc = __builtin_amdgcn_mfma_f32_16x16x32_bf16(a0h,b0h,acc,0,0,0);
      acc = __builtin_amdgcn_mfma_f32_16x16x32_bf16(a1h,b1h,acc,0,0,0);
      acc = __builtin_amdgcn_mfma_f32_16x16x32_bf16(a0h,b0m,acc,0,0,0);
      acc = __builtin_amdgcn_mfma_f32_16x16x32_bf16(a1h,b1m,acc,0,0,0);
      acc = __builtin_amdgcn_mfma_f32_16x16x32_bf16(a0h,b0l,acc,0,0,0);
      acc = __builtin_amdgcn_mfma_f32_16x16x32_bf16(a1h,b1l,acc,0,0,0);
      acc = __builtin_amdgcn_mfma_f32_16x16x32_bf16(a0l,b0h,acc,0,0,0);
      acc = __builtin_amdgcn_mfma_f32_16x16x32_bf16(a1l,b1h,acc,0,0,0);
      acc = __builtin_amdgcn_mfma_f32_16x16x32_bf16(a0l,b0m,acc,0,0,0);
      acc = __builtin_amdgcn_mfma_f32_16x16x32_bf16(a1l,b1m,acc,0,0,0);
      tq[q] = acc;
    }
    const int cc = w*16 + lm;
    #pragma unroll
    for (int r=0;r<4;r++){
      int e = lg*4 + r;
      int src = s_src[e];
      float y0=s_y[e*4+0], yx=s_y[e*4+1], yy=s_y[e*4+2], yz=s_y[e*4+3];
      float ss = s_up[src*128+cc];
      const float* vp = v_up + src*384 + cc*3;
      float vx=vp[0], vy=vp[1], vz=vp[2];
      float m1  = tq[0][r]*ss*y0;
      float t1s = tq[1][r]*ss;
      float t2y = tq[2][r]*y0;
      float m4  = tq[3][r]*(vx*yx+vy*yy+vz*yz)*0.5773502691896258f;
      int v0 = e*256 + cc*2;               // f32x4 index of (e, d'=cc*8)
      f32x4 o0; o0[0]=m1;     o0[1]=m4;     o0[2]=t1s*yx; o0[3]=t1s*yy;
      f32x4 o1; o1[0]=t1s*yz; o1[1]=t2y*vx; o1[2]=t2y*vy; o1[3]=t2y*vz;
      *(f32x4*)mjivec(v0)   = o0;
      *(f32x4*)mjivec(v0+1) = o1;
    }
  }
  __syncthreads();

  // ---- P3 (all 16 waves, MFMA exact-A x triple-B): gate1; LDS-atomic reduce ----
  {
    f32x4 acc0 = {0.f,0.f,0.f,0.f}, acc1 = {0.f,0.f,0.f,0.f};
    #pragma unroll
    for (int ik=0; ik<2; ik++){
      int kb = w*2 + ik;
      int v = lm*256 + kb*8 + lg*2;        // f32x4 index of (e=lm, d'=kb*32+lg*8)
      f32x4 fa = *(const f32x4*)mjivec(v);
      f32x4 fb = *(const f32x4*)mjivec(v+1);
      U16x8 ua;
      ua.u[0]=(unsigned short)f2bfbits(fa[0]); ua.u[1]=(unsigned short)f2bfbits(fa[1]);
      ua.u[2]=(unsigned short)f2bfbits(fa[2]); ua.u[3]=(unsigned short)f2bfbits(fa[3]);
      ua.u[4]=(unsigned short)f2bfbits(fb[0]); ua.u[5]=(unsigned short)f2bfbits(fb[1]);
      ua.u[6]=(unsigned short)f2bfbits(fb[2]); ua.u[7]=(unsigned short)f2bfbits(fb[3]);
      bf16x8 a = ua.b;
      #pragma unroll
      for (int p=0;p<3;p++){
        bf16x8 b0 = *(const bf16x8*)(wse1pk + p*32768 + (0*32+kb)*512 + l*8);
        bf16x8 b1 = *(const bf16x8*)(wse1pk + p*32768 + (1*32+kb)*512 + l*8);
        acc0 = __builtin_amdgcn_mfma_f32_16x16x32_bf16(a,b0,acc0,0,0,0);
        acc1 = __builtin_amdgcn_mfma_f32_16x16x32_bf16(a,b1,acc1,0,0,0);
      }
    }
    #pragma unroll
    for (int r=0;r<4;r++){
      int row = lg*4 + r;
      atomicAdd(partial + row*32 + lm,      acc0[r]);
      atomicAdd(partial + row*32 + 16 + lm, acc1[r]);
    }
  }
  __syncthreads();
  if (t < 512) { // silu(partial) -> sg1 hi/lo bf16
    int e = t>>5, jj = t&31;
    float g1 = siluf(partial[e*32+jj]);
    unsigned int hb = f2bfbits(g1);
    unsigned int lb = f2bfbits(g1 - __uint_as_float(hb<<16));
    *(unsigned short*)(smem + OFF_SG1H + e*64 + jj*2) = (unsigned short)hb;
    *(unsigned short*)(smem + OFF_SG1L + e*64 + jj*2) = (unsigned short)lb;
  }
  __syncthreads();

  // ---- P4 (all 16 waves, MFMA A hi/lo x B triple): gate2; sigmoid * f32 mji -> atomic scatter ----
  {
    bf16x8 ah = *(const bf16x8*)(smem + OFF_SG1H + lm*64 + lg*16);
    bf16x8 al = *(const bf16x8*)(smem + OFF_SG1L + lm*64 + lg*16);
    int de[4];
    #pragma unroll
    for (int r=0;r<4;r++) de[r] = s_dst[lg*4+r];
    #pragma unroll
    for (int nt4=0; nt4<4; nt4++){
      int nt = w*4 + nt4;
      const unsigned short* bp = wse2pk + nt*512 + l*8;
      bf16x8 b1 = *(const bf16x8*)(bp);
      bf16x8 b2 = *(const bf16x8*)(bp+32768);
      bf16x8 b3 = *(const bf16x8*)(bp+65536);
      f32x4 acc = {0.f,0.f,0.f,0.f};
      acc = __builtin_amdgcn_mfma_f32_16x16x32_bf16(ah,b1,acc,0,0,0);
      acc = __builtin_amdgcn_mfma_f32_16x16x32_bf16(ah,b2,acc,0,0,0);
      acc = __builtin_amdgcn_mfma_f32_16x16x32_bf16(ah,b3,acc,0,0,0);
      acc = __builtin_amdgcn_mfma_f32_16x16x32_bf16(al,b1,acc,0,0,0);
      acc = __builtin_amdgcn_mfma_f32_16x16x32_bf16(al,b2,acc,0,0,0);
      int col = nt*16 + lm;
      #pragma unroll
      for (int r=0;r<4;r++){
        int e = lg*4 + r;
        float gate = sigf(acc[r]);
        int word = e*1024 + col;
        float val = mjivec(word>>2)[word&3] * gate;
        unsafeAtomicAdd(accg + (size_t)de[r]*1024 + col, val);
      }
    }
  }
}

// ---------------- final node kernel: lin + skip einsum (8 nodes/block, value-preserving) ----------
__global__ __launch_bounds__(512) void node_out_kernel(
    const float* __restrict__ acc, const float* __restrict__ na,
    const float* __restrict__ Wl0, const float* __restrict__ Wl1,
    const float* __restrict__ Wsk0, const float* __restrict__ Wsk1,
    float* __restrict__ out)
{
  __shared__ float sacc[8*1024];
  __shared__ float smid_s[8][128];
  __shared__ float smid_v[8][128][3];
  __shared__ float sattr[8][10];
  const int t = threadIdx.x;
  const int n0 = blockIdx.x*8;
  {
    const float4* src4 = (const float4*)(acc + (size_t)n0*1024);
    float4* dst4 = (float4*)sacc;
    for (int i=t;i<2048;i+=512) dst4[i] = src4[i];
  }
  if (t < 80) sattr[t/10][t%10] = na[n0*10 + t];
  __syncthreads();
  const int v2 = t & 127, ns = t >> 7;     // ns handles nodes ns and ns+4
  const float* acA = sacc + ns*1024;
  const float* acB = sacc + (ns+4)*1024;
  float sA=0.f, a0A=0.f, a1A=0.f, a2A=0.f;
  float sB=0.f, a0B=0.f, a1B=0.f, a2B=0.f;
  for (int u=0;u<128;u++){
    float w0  = Wl0[u*128+v2];
    float w1  = Wl1[u*128+v2];
    float w0b = Wl0[(128+u)*128+v2];
    float w1b = Wl1[(128+u)*128+v2];
    const float* a8 = acA + u*8;
    sA += a8[0]*w0;  sA += a8[1]*w0b;
    a0A += a8[2]*w1;  a1A += a8[3]*w1;  a2A += a8[4]*w1;
    a0A += a8[5]*w1b; a1A += a8[6]*w1b; a2A += a8[7]*w1b;
    const float* b8 = acB + u*8;
    sB += b8[0]*w0;  sB += b8[1]*w0b;
    a0B += b8[2]*w1;  a1B += b8[3]*w1;  a2B += b8[4]*w1;
    a0B += b8[5]*w1b; a1B += b8[6]*w1b; a2B += b8[7]*w1b;
  }
  const float fl = 0.00390625f;   // (1/16 lin) * (1/16 avg_neigh)
  smid_s[ns][v2] = sA*fl;
  smid_v[ns][v2][0]=a0A*fl; smid_v[ns][v2][1]=a1A*fl; smid_v[ns][v2][2]=a2A*fl;
  smid_s[ns+4][v2] = sB*fl;
  smid_v[ns+4][v2][0]=a0B*fl; smid_v[ns+4][v2][1]=a1B*fl; smid_v[ns+4][v2][2]=a2B*fl;
  __syncthreads();
  float soA=0.f,o0A=0.f,o1A=0.f,o2A=0.f;
  float soB=0.f,o0B=0.f,o1B=0.f,o2B=0.f;
  for (int u=0;u<128;u++){
    float svA = smid_s[ns][u];
    float vA0 = smid_v[ns][u][0], vA1 = smid_v[ns][u][1], vA2 = smid_v[ns][u][2];
    float svB = smid_s[ns+4][u];
    float vB0 = smid_v[ns+4][u][0], vB1 = smid_v[ns+4][u][1], vB2 = smid_v[ns+4][u][2];
    const float* w0p = Wsk0 + u*1280 + v2;
    const float* w1p = Wsk1 + u*1280 + v2;
    #pragma unroll
    for (int wq=0;wq<10;wq++){
      float W0v = w0p[wq*128];
      float W1v = w1p[wq*128];
      float awA = sattr[ns][wq];
      float awB = sattr[ns+4][wq];
      soA += W0v*(svA*awA);
      o0A += W1v*(vA0*awA); o1A += W1v*(vA1*awA); o2A += W1v*(vA2*awA);
      soB += W0v*(svB*awB);
      o0B += W1v*(vB0*awB); o1B += W1v*(vB1*awB); o2B += W1v*(vB2*awB);
    }
  }
  const float fsk = 0.02795084971874737f;  // 1/sqrt(1280)
  float4 oA; oA.x = soA*fsk; oA.y = o0A*fsk; oA.z = o1A*fsk; oA.w = o2A*fsk;
  *(float4*)(out + (size_t)(n0+ns)*512 + v2*4) = oA;
  float4 oB; oB.x = soB*fsk; oB.y = o0B*fsk; oB.z = o1B*fsk; oB.w = o2B*fsk;
  *(float4*)(out + (size_t)(n0+ns+4)*512 + v2*4) = oB;
}

extern "C" void kernel_launch(void* const* d_in, const int* in_sizes, int n_in,
                              void* d_out, int out_size, void* d_ws, size_t ws_size,
                              hipStream_t stream) {
  const float* node_attrs = (const float*)d_in[0];
  const float* node_feats = (const float*)d_in[1];
  const float* edge_attrs = (const float*)d_in[2];
  const float* edge_feats = (const float*)d_in[3];
  const int*   edge_index = (const int*)d_in[4];
  const float* W_up0 = (const float*)d_in[5];
  const float* W_up1 = (const float*)d_in[6];
  const float* Wr1   = (const float*)d_in[7];
  const float* Wr2   = (const float*)d_in[8];
  const float* Wr3   = (const float*)d_in[9];
  const float* Wr4   = (const float*)d_in[10];
  const float* W_se1 = (const float*)d_in[11];
  const float* W_se2 = (const float*)d_in[12];
  const float* W_lin0= (const float*)d_in[13];
  const float* W_lin1= (const float*)d_in[14];
  const float* W_sk0 = (const float*)d_in[15];
  const float* W_sk1 = (const float*)d_in[16];

  float* ws   = (float*)d_ws;
  float* accg = ws;                      // N*1024 = 10,240,000 f32
  float* s_up = ws + 10240000;           // N*128
  float* v_up = s_up + 1280000;          // N*384
  unsigned short* wr4pk  = (unsigned short*)(v_up + 3840000);  // 98304 ushort (hi+mid+lo)
  unsigned short* wse1pk = wr4pk + 98304;                      // 98304
  unsigned short* wse2pk = wse1pk + 98304;                     // 98304

  hipMemsetAsync(accg, 0, (size_t)10240000*4, stream);
  pack_weights<<<128, 256, 0, stream>>>(Wr4, W_se1, W_se2, wr4pk, wse1pk, wse2pk);
  node_up_kernel<<<N_NODES, 128, 0, stream>>>(node_feats, W_up0, W_up1, s_up, v_up);
  edge_kernel<<<N_EDGES/16, 1024, 0, stream>>>(edge_feats, edge_attrs, edge_index,
      Wr1, Wr2, Wr3, wr4pk, wse1pk, wse2pk, s_up, v_up, accg);
  node_out_kernel<<<N_NODES/8, 512, 0, stream>>>(accg, node_attrs,
      W_lin0, W_lin1, W_sk0, W_sk1, (float*)d_out);
}

// Round 13
// 1082.908 us; speedup vs baseline: 1.3591x; 1.3591x over previous
//
#include <hip/hip_runtime.h>
#include <hip/hip_bf16.h>

#define N_NODES 10000
#define N_EDGES 160000

typedef __bf16 bf16x8 __attribute__((ext_vector_type(8)));
typedef float  f32x4  __attribute__((ext_vector_type(4)));
typedef unsigned short u16x8 __attribute__((ext_vector_type(8)));
union U16x8 { u16x8 u; bf16x8 b; };

__device__ __forceinline__ float sigf(float x){ return 1.0f/(1.0f+__expf(-x)); }
__device__ __forceinline__ float siluf(float x){ return x*sigf(x); }

__device__ __forceinline__ unsigned int f2bfbits(float f){
  unsigned int u = __float_as_uint(f);
  return (u + 0x7fffu + ((u>>16)&1u)) >> 16;
}
__device__ __forceinline__ void split3(float v, unsigned short* h, unsigned short* m, unsigned short* lo){
  unsigned int hb = f2bfbits(v); float hf = __uint_as_float(hb<<16);
  float r1 = v - hf;
  unsigned int mb = f2bfbits(r1); float mf = __uint_as_float(mb<<16);
  unsigned int lb = f2bfbits(r1 - mf);
  *h=(unsigned short)hb; *m=(unsigned short)mb; *lo=(unsigned short)lb;
}

// d' (permuted message dim) -> d (reference mji dim). d' = c*8 + slot.
__device__ __forceinline__ int dmap(int dp){
  int c = dp>>3, slot = dp&7;
  if (slot==0) return c;
  if (slot==1) return 128+c;
  if (slot<5)  return 256+3*c+(slot-2);
  return 640+3*c+(slot-5);
}

// ---------------- dst-sort prep kernels ----------------
__global__ void hist_kernel(const int* __restrict__ ei, int* __restrict__ hist){
  int e = blockIdx.x*256 + threadIdx.x;
  if (e < N_EDGES) atomicAdd(&hist[ei[N_EDGES+e]], 1);
}

// single block, 1024 threads: exclusive prefix sum of hist[10000] -> cursor
__global__ __launch_bounds__(1024) void scan_kernel(const int* __restrict__ hist, int* __restrict__ cursor){
  __shared__ int lsum[2][1024];
  const int t = threadIdx.x;
  int s = 0;
  if (t < 1000){
    #pragma unroll
    for (int i=0;i<10;i++) s += hist[t*10+i];
  }
  lsum[0][t] = s;
  __syncthreads();
  int src = 0;
  for (int off=1; off<1024; off<<=1){
    int v = lsum[src][t];
    if (t >= off) v += lsum[src][t-off];
    lsum[src^1][t] = v;
    __syncthreads();
    src ^= 1;
  }
  if (t < 1000){
    int run = t ? lsum[src][t-1] : 0;
    #pragma unroll
    for (int i=0;i<10;i++){ cursor[t*10+i] = run; run += hist[t*10+i]; }
  }
}

__global__ void scatter_kernel(const int* __restrict__ ei, int* __restrict__ cursor, int* __restrict__ perm){
  int e = blockIdx.x*256 + threadIdx.x;
  if (e < N_EDGES){
    int d = ei[N_EDGES+e];
    int pos = atomicAdd(&cursor[d], 1);
    perm[pos] = e;
  }
}

// ---------------- pack weights: TRIPLE-split bf16 B-fragments (verified R10) ----------------
__global__ void pack_weights(const float* __restrict__ Wr4,
                             const float* __restrict__ Wse1,
                             const float* __restrict__ Wse2,
                             unsigned short* __restrict__ wr4pk,
                             unsigned short* __restrict__ wse1pk,
                             unsigned short* __restrict__ wse2pk)
{
  int t = blockIdx.x*256 + threadIdx.x;   // 0..32767
  int j = t&7, l = (t>>3)&63;
  int lg = l>>4, lm = l&15;
  { // wr4pk
    int ks = (t>>9)&1; int nt = t>>10;
    int k = ks*32 + lg*8 + j;
    int col = nt*16 + lm;
    split3(Wr4[k*512+col]*0.125f, wr4pk+t, wr4pk+t+32768, wr4pk+t+65536);
  }
  { // wse1pk
    int kb = (t>>9)&31; int nt = t>>14;
    int d = dmap(kb*32 + lg*8 + j);
    int col = nt*16 + lm;
    split3(Wse1[d*32+col], wse1pk+t, wse1pk+t+32768, wse1pk+t+65536);
  }
  { // wse2pk
    int nt = t>>9;
    int krow = lg*8 + j;
    int d = dmap(nt*16 + lm);
    split3(Wse2[krow*1024+d], wse2pk+t, wse2pk+t+32768, wse2pk+t+65536);
  }
}

// ---------------- node up-projection (exact R6) ----------------
__global__ __launch_bounds__(128) void node_up_kernel(
    const float* __restrict__ nf, const float* __restrict__ W0, const float* __restrict__ W1,
    float* __restrict__ s_up, float* __restrict__ v_up)
{
  int n = blockIdx.x; int c = threadIdx.x;
  __shared__ float row[512];
  #pragma unroll
  for (int i=0;i<4;i++) row[c + 128*i] = nf[n*512 + c + 128*i];
  __syncthreads();
  float as=0.f, a0=0.f, a1=0.f, a2=0.f;
  for (int u=0;u<128;u++){
    float w0 = W0[u*128+c], w1 = W1[u*128+c];
    as += row[u]*w0;
    a0 += row[128+u*3+0]*w1;
    a1 += row[128+u*3+1]*w1;
    a2 += row[128+u*3+2]*w1;
  }
  const float f = 0.08838834764831845f;   // 1/sqrt(128)
  s_up[n*128+c] = as*f;
  v_up[n*384 + c*3+0] = a0*f;
  v_up[n*384 + c*3+1] = a1*f;
  v_up[n*384 + c*3+2] = a2*f;
}

// ---------------- fused edge kernel: R10 body + dst-sorted edges + segmented flush --------------
// 1024 threads, 16 dst-sorted edges/block. LDS layout (bytes) — exact R10:
//  [0,16384)      : hA(16x64 f32)@0, hB@4096 during P1; partial[8][16][32] f32 during P3
//  [16384,81920)  : mji f32 [16 e][1024 d'], vec-XOR-swizzled (see mjivec); P4 overwrites with vals
//  [81920,83968)  : h3 hi bf16 [16][64], XOR-swizzled: byte ^= (row&7)<<4
//  [83968,86016)  : h3 lo
//  [86016,87040)  : sg1 hi bf16 [16][32]
//  [87040,88064)  : sg1 lo
//  [88064,...)    : s_src[16], s_dst[16], s_y[16][4]
#define OFF_MJI  16384
#define OFF_H3H  81920
#define OFF_H3L  83968
#define OFF_SG1H 86016
#define OFF_SG1L 87040
#define OFF_SRC  88064
#define OFF_DST  88128
#define OFF_Y    88192

__global__ __launch_bounds__(1024, 1) void edge_kernel(
    const float* __restrict__ ef, const float* __restrict__ ea, const int* __restrict__ ei,
    const int* __restrict__ perm,
    const float* __restrict__ Wr1, const float* __restrict__ Wr2, const float* __restrict__ Wr3,
    const unsigned short* __restrict__ wr4pk, const unsigned short* __restrict__ wse1pk,
    const unsigned short* __restrict__ wse2pk,
    const float* __restrict__ s_up, const float* __restrict__ v_up, float* __restrict__ accg)
{
  __shared__ __align__(16) char smem[88448];
  float* hA = (float*)smem;
  float* hB = (float*)(smem + 4096);
  float* partial = (float*)smem;
  int*   s_src = (int*)(smem + OFF_SRC);
  int*   s_dst = (int*)(smem + OFF_DST);
  float* s_y   = (float*)(smem + OFF_Y);

  const int t = threadIdx.x;
  const int e0 = blockIdx.x * 16;
  const int l = t & 63, w = t >> 6;        // lane, wave (0..15)
  const int lg = l >> 4, lm = l & 15;

  // swizzled mji accessor: v = f32x4 index in [0,4096)
  auto mjivec = [&](int v) -> float* {
    int p = v ^ ((v>>3)&7) ^ ((v>>8)&7);
    return (float*)(smem + OFF_MJI + p*16);
  };

  if (t < 16){ int pe = perm[e0+t]; s_src[t] = ei[pe]; s_dst[t] = ei[N_EDGES + pe]; }
  else if (t >= 64 && t < 128){
    int q = t-64;
    int pe = perm[e0 + (q>>2)];
    s_y[(q>>2)*4 + (q&3)] = ea[pe*4 + (q&3)];
  }

  // ---- P1 (R10): MLP 8->64->64->64 (+silu); h3 -> hi/lo bf16 (swizzled) ----
  {
    const int i = t & 63, eh = t >> 6;
    int pe = perm[e0 + eh];                // 16 distinct values, cache-broadcast
    float r;
    { float a0=0.f;
      #pragma unroll
      for (int k=0;k<8;k++) a0 += ef[pe*8+k]*Wr1[k*64+i];
      r = siluf(a0*0.35355339059327373f);
    }
    hA[eh*64+i]=r;
    __syncthreads();
    { float a0=0.f;
      for (int k=0;k<64;k++) a0 += hA[eh*64+k]*Wr2[k*64+i];
      r = siluf(a0*0.125f);
    }
    hB[eh*64+i]=r;
    __syncthreads();
    { float a0=0.f;
      for (int k=0;k<64;k++) a0 += hB[eh*64+k]*Wr3[k*64+i];
      r = siluf(a0*0.125f);
    }
    unsigned int hb = f2bfbits(r);
    unsigned int lb = f2bfbits(r - __uint_as_float(hb<<16));
    int o = (eh*128 + i*2) ^ ((eh&7)<<4);
    *(unsigned short*)(smem + OFF_H3H + o) = (unsigned short)hb;
    *(unsigned short*)(smem + OFF_H3L + o) = (unsigned short)lb;
  }
  __syncthreads();

  // ---- P2 (waves 0..7, MFMA A hi/lo x B triple): tpw + messages -> mji f32 (swizzled) ----
  if (w < 8) {
    int oa0 = (lm*128 +  0 + lg*16) ^ ((lm&7)<<4);
    int oa1 = (lm*128 + 64 + lg*16) ^ ((lm&7)<<4);
    bf16x8 a0h = *(const bf16x8*)(smem + OFF_H3H + oa0);
    bf16x8 a1h = *(const bf16x8*)(smem + OFF_H3H + oa1);
    bf16x8 a0l = *(const bf16x8*)(smem + OFF_H3L + oa0);
    bf16x8 a1l = *(const bf16x8*)(smem + OFF_H3L + oa1);
    f32x4 tq[4];
    #pragma unroll
    for (int q=0;q<4;q++){
      int nt = q*8 + w;                    // wave w owns cols q*128 + w*16 + lm for all q
      const unsigned short* bp0 = wr4pk + (nt*2+0)*512 + l*8;
      const unsigned short* bp1 = wr4pk + (nt*2+1)*512 + l*8;
      bf16x8 b0h = *(const bf16x8*)(bp0);
      bf16x8 b0m = *(const bf16x8*)(bp0+32768);
      bf16x8 b0l = *(const bf16x8*)(bp0+65536);
      bf16x8 b1h = *(const bf16x8*)(bp1);
      bf16x8 b1m = *(const bf16x8*)(bp1+32768);
      bf16x8 b1l = *(const bf16x8*)(bp1+65536);
      f32x4 acc = {0.f,0.f,0.f,0.f};
      acc = __builtin_amdgcn_mfma_f32_16x16x32_bf16(a0h,b0h,acc,0,0,0);
      acc = __builtin_amdgcn_mfma_f32_16x16x32_bf16(a1h,b1h,acc,0,0,0);
      acc = __builtin_amdgcn_mfma_f32_16x16x32_bf16(a0h,b0m,acc,0,0,0);
      acc = __builtin_amdgcn_mfma_f32_16x16x32_bf16(a1h,b1m,acc,0,0,0);
      acc = __builtin_amdgcn_mfma_f32_16x16x32_bf16(a0h,b0l,acc,0,0,0);
      acc = __builtin_amdgcn_mfma_f32_16x16x32_bf16(a1h,b1l,acc,0,0,0);
      acc = __builtin_amdgcn_mfma_f32_16x16x32_bf16(a0l,b0h,acc,0,0,0);
      acc = __builtin_amdgcn_mfma_f32_16x16x32_bf16(a1l,b1h,acc,0,0,0);
      acc = __builtin_amdgcn_mfma_f32_16x16x32_bf16(a0l,b0m,acc,0,0,0);
      acc = __builtin_amdgcn_mfma_f32_16x16x32_bf16(a1l,b1m,acc,0,0,0);
      tq[q] = acc;
    }
    const int cc = w*16 + lm;
    #pragma unroll
    for (int r=0;r<4;r++){
      int e = lg*4 + r;
      int src = s_src[e];
      float y0=s_y[e*4+0], yx=s_y[e*4+1], yy=s_y[e*4+2], yz=s_y[e*4+3];
      float ss = s_up[src*128+cc];
      const float* vp = v_up + src*384 + cc*3;
      float vx=vp[0], vy=vp[1], vz=vp[2];
      float m1  = tq[0][r]*ss*y0;
      float t1s = tq[1][r]*ss;
      float t2y = tq[2][r]*y0;
      float m4  = tq[3][r]*(vx*yx+vy*yy+vz*yz)*0.5773502691896258f;
      int v0 = e*256 + cc*2;               // f32x4 index of (e, d'=cc*8)
      f32x4 o0; o0[0]=m1;     o0[1]=m4;     o0[2]=t1s*yx; o0[3]=t1s*yy;
      f32x4 o1; o1[0]=t1s*yz; o1[1]=t2y*vx; o1[2]=t2y*vy; o1[3]=t2y*vz;
      *(f32x4*)mjivec(v0)   = o0;
      *(f32x4*)mjivec(v0+1) = o1;
    }
  }
  __syncthreads();

  // ---- P3 (waves 0..7, MFMA exact-A x triple-B): gate1; partial stores (R10) ----
  if (w < 8) {
    f32x4 acc0 = {0.f,0.f,0.f,0.f}, acc1 = {0.f,0.f,0.f,0.f};
    #pragma unroll
    for (int ik=0; ik<4; ik++){
      int kb = w*4 + ik;
      int v = lm*256 + kb*8 + lg*2;        // f32x4 index of (e=lm, d'=kb*32+lg*8)
      f32x4 fa = *(const f32x4*)mjivec(v);
      f32x4 fb = *(const f32x4*)mjivec(v+1);
      U16x8 ua;
      ua.u[0]=(unsigned short)f2bfbits(fa[0]); ua.u[1]=(unsigned short)f2bfbits(fa[1]);
      ua.u[2]=(unsigned short)f2bfbits(fa[2]); ua.u[3]=(unsigned short)f2bfbits(fa[3]);
      ua.u[4]=(unsigned short)f2bfbits(fb[0]); ua.u[5]=(unsigned short)f2bfbits(fb[1]);
      ua.u[6]=(unsigned short)f2bfbits(fb[2]); ua.u[7]=(unsigned short)f2bfbits(fb[3]);
      bf16x8 a = ua.b;
      #pragma unroll
      for (int p=0;p<3;p++){
        bf16x8 b0 = *(const bf16x8*)(wse1pk + p*32768 + (0*32+kb)*512 + l*8);
        bf16x8 b1 = *(const bf16x8*)(wse1pk + p*32768 + (1*32+kb)*512 + l*8);
        acc0 = __builtin_amdgcn_mfma_f32_16x16x32_bf16(a,b0,acc0,0,0,0);
        acc1 = __builtin_amdgcn_mfma_f32_16x16x32_bf16(a,b1,acc1,0,0,0);
      }
    }
    #pragma unroll
    for (int r=0;r<4;r++){
      int row = lg*4 + r;
      partial[(w*16+row)*32 + lm     ] = acc0[r];
      partial[(w*16+row)*32 + 16+lm  ] = acc1[r];
    }
  }
  __syncthreads();
  if (t < 512) { // reduce 8 partials + silu -> sg1 hi/lo bf16 (R10)
    int e = t>>5, jj = t&31;
    float s = 0.f;
    #pragma unroll
    for (int w8=0; w8<8; w8++) s += partial[(w8*16+e)*32 + jj];
    float g1 = siluf(s);
    unsigned int hb = f2bfbits(g1);
    unsigned int lb = f2bfbits(g1 - __uint_as_float(hb<<16));
    *(unsigned short*)(smem + OFF_SG1H + e*64 + jj*2) = (unsigned short)hb;
    *(unsigned short*)(smem + OFF_SG1L + e*64 + jj*2) = (unsigned short)lb;
  }
  __syncthreads();

  // ---- P4 (all 16 waves, MFMA A hi/lo x B triple): gate2; val = gate*mji IN PLACE ----
  {
    bf16x8 ah = *(const bf16x8*)(smem + OFF_SG1H + lm*64 + lg*16);
    bf16x8 al = *(const bf16x8*)(smem + OFF_SG1L + lm*64 + lg*16);
    #pragma unroll
    for (int nt4=0; nt4<4; nt4++){
      int nt = w*4 + nt4;
      const unsigned short* bp = wse2pk + nt*512 + l*8;
      bf16x8 b1 = *(const bf16x8*)(bp);
      bf16x8 b2 = *(const bf16x8*)(bp+32768);
      bf16x8 b3 = *(const bf16x8*)(bp+65536);
      f32x4 acc = {0.f,0.f,0.f,0.f};
      acc = __builtin_amdgcn_mfma_f32_16x16x32_bf16(ah,b1,acc,0,0,0);
      acc = __builtin_amdgcn_mfma_f32_16x16x32_bf16(ah,b2,acc,0,0,0);
      acc = __builtin_amdgcn_mfma_f32_16x16x32_bf16(ah,b3,acc,0,0,0);
      acc = __builtin_amdgcn_mfma_f32_16x16x32_bf16(al,b1,acc,0,0,0);
      acc = __builtin_amdgcn_mfma_f32_16x16x32_bf16(al,b2,acc,0,0,0);
      int col = nt*16 + lm;
      #pragma unroll
      for (int r=0;r<4;r++){
        int e = lg*4 + r;
        float gate = sigf(acc[r]);
        int word = e*1024 + col;
        float* p = mjivec(word>>2) + (word&3);
        *p = *p * gate;
      }
    }
  }
  __syncthreads();

  // ---- P5: per-column segmented reduce over dst-sorted edges -> few coalesced atomics ----
  {
    const int dp = t;
    int cur = s_dst[0];
    int w0 = dp;                           // e=0: word = dp
    float run = mjivec(w0>>2)[w0&3];
    #pragma unroll
    for (int e=1;e<16;e++){
      int d = s_dst[e];
      int wd = e*1024 + dp;
      float v = mjivec(wd>>2)[wd&3];
      if (d == cur) run += v;
      else {
        unsafeAtomicAdd(accg + (size_t)cur*1024 + dp, run);
        cur = d; run = v;
      }
    }
    unsafeAtomicAdd(accg + (size_t)cur*1024 + dp, run);
  }
}

// ---------------- final node kernel: lin + skip einsum (8 nodes/block, value-preserving) ----------
__global__ __launch_bounds__(512) void node_out_kernel(
    const float* __restrict__ acc, const float* __restrict__ na,
    const float* __restrict__ Wl0, const float* __restrict__ Wl1,
    const float* __restrict__ Wsk0, const float* __restrict__ Wsk1,
    float* __restrict__ out)
{
  __shared__ float sacc[8*1024];
  __shared__ float smid_s[8][128];
  __shared__ float smid_v[8][128][3];
  __shared__ float sattr[8][10];
  const int t = threadIdx.x;
  const int n0 = blockIdx.x*8;
  {
    const float4* src4 = (const float4*)(acc + (size_t)n0*1024);
    float4* dst4 = (float4*)sacc;
    for (int i=t;i<2048;i+=512) dst4[i] = src4[i];
  }
  if (t < 80) sattr[t/10][t%10] = na[n0*10 + t];
  __syncthreads();
  const int v2 = t & 127, ns = t >> 7;     // ns handles nodes ns and ns+4
  const float* acA = sacc + ns*1024;
  const float* acB = sacc + (ns+4)*1024;
  float sA=0.f, a0A=0.f, a1A=0.f, a2A=0.f;
  float sB=0.f, a0B=0.f, a1B=0.f, a2B=0.f;
  for (int u=0;u<128;u++){
    float w0  = Wl0[u*128+v2];
    float w1  = Wl1[u*128+v2];
    float w0b = Wl0[(128+u)*128+v2];
    float w1b = Wl1[(128+u)*128+v2];
    const float* a8 = acA + u*8;
    sA += a8[0]*w0;  sA += a8[1]*w0b;
    a0A += a8[2]*w1;  a1A += a8[3]*w1;  a2A += a8[4]*w1;
    a0A += a8[5]*w1b; a1A += a8[6]*w1b; a2A += a8[7]*w1b;
    const float* b8 = acB + u*8;
    sB += b8[0]*w0;  sB += b8[1]*w0b;
    a0B += b8[2]*w1;  a1B += b8[3]*w1;  a2B += b8[4]*w1;
    a0B += b8[5]*w1b; a1B += b8[6]*w1b; a2B += b8[7]*w1b;
  }
  const float fl = 0.00390625f;   // (1/16 lin) * (1/16 avg_neigh)
  smid_s[ns][v2] = sA*fl;
  smid_v[ns][v2][0]=a0A*fl; smid_v[ns][v2][1]=a1A*fl; smid_v[ns][v2][2]=a2A*fl;
  smid_s[ns+4][v2] = sB*fl;
  smid_v[ns+4][v2][0]=a0B*fl; smid_v[ns+4][v2][1]=a1B*fl; smid_v[ns+4][v2][2]=a2B*fl;
  __syncthreads();
  float soA=0.f,o0A=0.f,o1A=0.f,o2A=0.f;
  float soB=0.f,o0B=0.f,o1B=0.f,o2B=0.f;
  for (int u=0;u<128;u++){
    float svA = smid_s[ns][u];
    float vA0 = smid_v[ns][u][0], vA1 = smid_v[ns][u][1], vA2 = smid_v[ns][u][2];
    float svB = smid_s[ns+4][u];
    float vB0 = smid_v[ns+4][u][0], vB1 = smid_v[ns+4][u][1], vB2 = smid_v[ns+4][u][2];
    const float* w0p = Wsk0 + u*1280 + v2;
    const float* w1p = Wsk1 + u*1280 + v2;
    #pragma unroll
    for (int wq=0;wq<10;wq++){
      float W0v = w0p[wq*128];
      float W1v = w1p[wq*128];
      float awA = sattr[ns][wq];
      float awB = sattr[ns+4][wq];
      soA += W0v*(svA*awA);
      o0A += W1v*(vA0*awA); o1A += W1v*(vA1*awA); o2A += W1v*(vA2*awA);
      soB += W0v*(svB*awB);
      o0B += W1v*(vB0*awB); o1B += W1v*(vB1*awB); o2B += W1v*(vB2*awB);
    }
  }
  const float fsk = 0.02795084971874737f;  // 1/sqrt(1280)
  float4 oA; oA.x = soA*fsk; oA.y = o0A*fsk; oA.z = o1A*fsk; oA.w = o2A*fsk;
  *(float4*)(out + (size_t)(n0+ns)*512 + v2*4) = oA;
  float4 oB; oB.x = soB*fsk; oB.y = o0B*fsk; oB.z = o1B*fsk; oB.w = o2B*fsk;
  *(float4*)(out + (size_t)(n0+ns+4)*512 + v2*4) = oB;
}

extern "C" void kernel_launch(void* const* d_in, const int* in_sizes, int n_in,
                              void* d_out, int out_size, void* d_ws, size_t ws_size,
                              hipStream_t stream) {
  const float* node_attrs = (const float*)d_in[0];
  const float* node_feats = (const float*)d_in[1];
  const float* edge_attrs = (const float*)d_in[2];
  const float* edge_feats = (const float*)d_in[3];
  const int*   edge_index = (const int*)d_in[4];
  const float* W_up0 = (const float*)d_in[5];
  const float* W_up1 = (const float*)d_in[6];
  const float* Wr1   = (const float*)d_in[7];
  const float* Wr2   = (const float*)d_in[8];
  const float* Wr3   = (const float*)d_in[9];
  const float* Wr4   = (const float*)d_in[10];
  const float* W_se1 = (const float*)d_in[11];
  const float* W_se2 = (const float*)d_in[12];
  const float* W_lin0= (const float*)d_in[13];
  const float* W_lin1= (const float*)d_in[14];
  const float* W_sk0 = (const float*)d_in[15];
  const float* W_sk1 = (const float*)d_in[16];

  float* ws   = (float*)d_ws;
  float* accg = ws;                      // N*1024 = 10,240,000 f32
  float* s_up = ws + 10240000;           // N*128
  float* v_up = s_up + 1280000;          // N*384
  unsigned short* wr4pk  = (unsigned short*)(v_up + 3840000);  // 98304 ushort (hi+mid+lo)
  unsigned short* wse1pk = wr4pk + 98304;                      // 98304
  unsigned short* wse2pk = wse1pk + 98304;                     // 98304
  int* hist   = (int*)(wse2pk + 98304);                        // 10000
  int* cursor = hist + 10000;                                  // 10000
  int* perm   = cursor + 10000;                                // 160000

  hipMemsetAsync(accg, 0, (size_t)10240000*4, stream);
  hipMemsetAsync(hist, 0, 10000*4, stream);
  hist_kernel<<<(N_EDGES+255)/256, 256, 0, stream>>>(edge_index, hist);
  scan_kernel<<<1, 1024, 0, stream>>>(hist, cursor);
  scatter_kernel<<<(N_EDGES+255)/256, 256, 0, stream>>>(edge_index, cursor, perm);
  pack_weights<<<128, 256, 0, stream>>>(Wr4, W_se1, W_se2, wr4pk, wse1pk, wse2pk);
  node_up_kernel<<<N_NODES, 128, 0, stream>>>(node_feats, W_up0, W_up1, s_up, v_up);
  edge_kernel<<<N_EDGES/16, 1024, 0, stream>>>(edge_feats, edge_attrs, edge_index, perm,
      Wr1, Wr2, Wr3, wr4pk, wse1pk, wse2pk, s_up, v_up, accg);
  node_out_kernel<<<N_NODES/8, 512, 0, stream>>>(accg, node_attrs,
      W_lin0, W_lin1, W_sk0, W_sk1, (float*)d_out);
}